// Round 2
// baseline (28592.154 us; speedup 1.0000x reference)
//
#include <hip/hip_runtime.h>
#include <hip/hip_bf16.h>
#include <math.h>

typedef unsigned int u32;
typedef unsigned long long u64;

#define STRIDE 262656          // >= max column length 262242, per-column stride in floats
#define ACT_PRELU 0
#define ACT_RELU  1
#define ACT_ELU   2

// float -> key such that ascending key order == descending float order
__device__ __forceinline__ u32 f2k(float f){
    u32 u = __float_as_uint(f);
    return (u & 0x80000000u) ? u : (u ^ 0x7FFFFFFFu);
}
__device__ __forceinline__ float k2f(u32 k){
    u32 u = (k & 0x80000000u) ? k : (k ^ 0x7FFFFFFFu);
    return __uint_as_float(u);
}

// ---------------- layer-0 conv: x[262144][16] -> fold widths -> conv K=99 pad=98 ----------------
__global__ __launch_bounds__(256) void conv0_k(const float* __restrict__ x, float* __restrict__ Out,
                                               const float* __restrict__ w0, const float* __restrict__ b0)
{
    __shared__ float s0[354];   // 256 + 98
    __shared__ float sw[198];
    const int wp = blockIdx.y;
    const int h0 = blockIdx.x * 256;
    const int tid = threadIdx.x;
    for (int t = tid; t < 354; t += 256){
        int h = h0 - 98 + t;
        float v = 0.f;
        if (h >= 0 && h < 262144) v = x[(size_t)h*16 + 2*wp] + x[(size_t)h*16 + 2*wp + 1];
        s0[t] = v;
    }
    if (tid < 198) sw[tid] = w0[tid];
    __syncthreads();
    int hp = h0 + tid;
    if (hp < 262242){
        float a0 = 2.f*b0[0], a1v = 2.f*b0[1];   // fold doubles bias
        for (int j = 0; j < 99; j++){
            float xv = s0[tid + j];
            a0  += sw[j]      * xv;
            a1v += sw[99 + j] * xv;
        }
        Out[(size_t)(0*8 + wp)*STRIDE + hp] = a0;
        Out[(size_t)(1*8 + wp)*STRIDE + hp] = a1v;
    }
}

// ---------------- generic conv along H, column-major buffers ----------------
// In col layout: (c*Wi + w)*STRIDE + h.  Out: (o*Wo + wp)*STRIDE + h'.
// foldIn: input width pair-summed (Wi -> Wo pairing), bias scaled by bscale.
template<int INC, int OUTC>
__global__ __launch_bounds__(256) void conv_t(
    const float* __restrict__ In, float* __restrict__ Out,
    const float* __restrict__ Wt, const float* __restrict__ Bs,
    int Hin, int Hout, int K, int pad, int Wi, int Wo, int foldIn, float bscale)
{
    __shared__ float sIn[INC][613];          // 256 + 358 - 1 max
    __shared__ float sW[OUTC*INC*358];
    const int wp = blockIdx.y;
    const int h0 = blockIdx.x * 256;
    const int tid = threadIdx.x;
    const int tl = 256 + K - 1;
    for (int t = tid; t < INC*tl; t += 256){
        int c = t / tl, r = t - c*tl;
        int h = h0 - pad + r;
        float v = 0.f;
        if (h >= 0 && h < Hin){
            if (foldIn) v = In[(size_t)(c*Wi + 2*wp)*STRIDE + h] + In[(size_t)(c*Wi + 2*wp + 1)*STRIDE + h];
            else        v = In[(size_t)(c*Wi + wp)*STRIDE + h];
        }
        sIn[c][r] = v;
    }
    for (int t = tid; t < OUTC*INC*K; t += 256) sW[t] = Wt[t];
    __syncthreads();
    int hp = h0 + tid;
    if (hp < Hout){
        float acc[OUTC];
        #pragma unroll
        for (int o = 0; o < OUTC; o++) acc[o] = bscale * Bs[o];
        for (int c = 0; c < INC; c++){
            for (int j = 0; j < K; j++){
                float xv = sIn[c][tid + j];
                #pragma unroll
                for (int o = 0; o < OUTC; o++) acc[o] += sW[(o*INC + c)*K + j] * xv;
            }
        }
        #pragma unroll
        for (int o = 0; o < OUTC; o++) Out[(size_t)(o*Wo + wp)*STRIDE + hp] = acc[o];
    }
}

// ---------------- per-column descending radix sort (one block per column) ----------------
// bA holds conv-output floats; keys mapped in place; 4 LSD passes ping-pong bA<->bB;
// final pass writes activated / truncated / C-duplicated floats into dstA (== bA region).
#define SBT 1024
#define SWV 16
#define ER  4
#define CHUNK (SBT*ER)

__global__ __launch_bounds__(SBT) void sort_cols(
    u32* __restrict__ bA, u32* __restrict__ bB, float* __restrict__ dstA,
    const float* __restrict__ alphaPtr,
    int N, int kOut, int dup, int act)
{
    const int col = blockIdx.x;
    u32* p0 = bA + (size_t)col*STRIDE;
    u32* p1 = bB + (size_t)col*STRIDE;
    float* dst = dstA + (size_t)col*STRIDE;
    const int tid  = threadIdx.x;
    const int lane = tid & 63;
    const int wave = tid >> 6;
    const u64 lt = (1ull << lane) - 1ull;
    const float alpha = (act == ACT_PRELU) ? alphaPtr[0] : 0.f;

    __shared__ u32 hist[256];
    __shared__ u32 off[256];
    __shared__ u32 sc[256];
    __shared__ u32 tot[256];
    __shared__ unsigned short cntE[ER][SWV][256];   // counts -> in-place prefixes; kept zeroed

    for (int t = tid; t < ER*SWV*256; t += SBT) ((unsigned short*)cntE)[t] = 0;
    __syncthreads();

    for (int pass = 0; pass < 4; pass++){
        const int sh = pass * 8;
        u32* src = (pass & 1) ? p1 : p0;
        u32* dk  = (pass & 1) ? p0 : p1;

        // ---- histogram (pass 0 also maps float->key in place) ----
        if (tid < 256) hist[tid] = 0;
        __syncthreads();
        for (int i = tid; i < N; i += SBT){
            u32 key;
            if (pass == 0){ key = f2k(__uint_as_float(src[i])); src[i] = key; }
            else key = src[i];
            u32 dig = (key >> sh) & 255u;
            u64 same = __ballot(1);
            #pragma unroll
            for (int b = 0; b < 8; b++){
                u64 bb = __ballot((dig >> b) & 1u);
                same &= ((dig >> b) & 1u) ? bb : ~bb;
            }
            if ((same & lt) == 0) atomicAdd(&hist[dig], (u32)__popcll(same));
        }
        __syncthreads();
        // exclusive scan hist -> off
        if (tid < 256) sc[tid] = hist[tid];
        __syncthreads();
        for (int s = 1; s < 256; s <<= 1){
            u32 v = (tid < 256 && tid >= s) ? sc[tid - s] : 0u;
            __syncthreads();
            if (tid < 256) sc[tid] += v;
            __syncthreads();
        }
        if (tid < 256) off[tid] = sc[tid] - hist[tid];
        __syncthreads();

        // ---- stable scatter, chunks of 4096 (order: e-round major, tid minor) ----
        const int nch = (N + CHUNK - 1) / CHUNK;
        for (int ch = 0; ch < nch; ch++){
            const int base = ch * CHUNK;
            u32 key[ER], dig[ER]; int rnk[ER]; bool val[ER], led[ER];
            #pragma unroll
            for (int e = 0; e < ER; e++){
                int i = base + e*SBT + tid;
                val[e] = (i < N);
                key[e] = val[e] ? src[i] : 0u;
                dig[e] = (key[e] >> sh) & 255u;
                u64 same = __ballot(val[e]);
                #pragma unroll
                for (int b = 0; b < 8; b++){
                    u64 bb = __ballot(val[e] && ((dig[e] >> b) & 1u));
                    same &= ((dig[e] >> b) & 1u) ? bb : ~bb;
                }
                rnk[e] = (int)__popcll(same & lt);
                led[e] = val[e] && (rnk[e] == 0);
                if (led[e]) cntE[e][wave][dig[e]] = (unsigned short)__popcll(same);
            }
            __syncthreads();
            // per-digit serial prefix over (e, wave); write prefix only where count != 0
            if (tid < 256){
                u32 t = 0;
                #pragma unroll
                for (int e = 0; e < ER; e++)
                    for (int w = 0; w < SWV; w++){
                        u32 c = cntE[e][w][tid];
                        if (c){ cntE[e][w][tid] = (unsigned short)t; t += c; }
                    }
                tot[tid] = t;
            }
            __syncthreads();
            #pragma unroll
            for (int e = 0; e < ER; e++){
                if (val[e]){
                    u32 pos = off[dig[e]] + (u32)cntE[e][wave][dig[e]] + (u32)rnk[e];
                    if (pass < 3){
                        dk[pos] = key[e];
                    } else {
                        float v = k2f(key[e]);
                        if (act == ACT_PRELU)      v = (v >= 0.f) ? v : alpha * v;
                        else if (act == ACT_RELU)  v = (v > 0.f) ? v : 0.f;
                        else                       v = (v > 0.f) ? v : expm1f(v);
                        if (dup == 1){
                            if ((int)pos < kOut) dst[pos] = v;
                        } else {
                            int bse = (int)pos * dup;
                            if (bse < kOut){
                                for (int d = 0; d < dup; d++) dst[bse + d] = v;
                            }
                        }
                    }
                }
            }
            __syncthreads();
            if (tid < 256) off[tid] += tot[tid];
            #pragma unroll
            for (int e = 0; e < ER; e++) if (led[e]) cntE[e][wave][dig[e]] = 0;
            __syncthreads();
        }
        __syncthreads();
    }
}

// ---------------- FC (5x1600 @ 1600x200) + log_softmax over 1000 ----------------
__global__ __launch_bounds__(1024) void fc_lsm(const float* __restrict__ A, const float* __restrict__ Wfc,
                                               const float* __restrict__ bfc, float* __restrict__ out)
{
    const int tid = threadIdx.x;
    __shared__ float red[1024];
    float logit = -INFINITY;
    if (tid < 1000){
        int o = tid / 200, j = tid - o*200;
        float acc = bfc[j];
        const float* wrow = Wfc + (size_t)j*1600;
        for (int q = 0; q < 1600; q++){
            int p = q >> 1, wq = q & 1;
            acc += wrow[q] * A[(size_t)(o*2 + wq)*STRIDE + p];
        }
        logit = acc;
    }
    red[tid] = logit;
    __syncthreads();
    for (int s = 512; s > 0; s >>= 1){
        if (tid < s) red[tid] = fmaxf(red[tid], red[tid + s]);
        __syncthreads();
    }
    float m = red[0];
    __syncthreads();
    red[tid] = (tid < 1000) ? expf(logit - m) : 0.f;
    __syncthreads();
    for (int s = 512; s > 0; s >>= 1){
        if (tid < s) red[tid] += red[tid + s];
        __syncthreads();
    }
    float lse = logf(red[0]);
    if (tid < 1000) out[tid] = logit - m - lse;
}

extern "C" void kernel_launch(void* const* d_in, const int* in_sizes, int n_in,
                              void* d_out, int out_size, void* d_ws, size_t ws_size,
                              hipStream_t stream)
{
    (void)in_sizes; (void)n_in; (void)out_size;
    // workspace guard: need 2 ping-pong buffers of 16 columns x STRIDE floats
    if (ws_size < (size_t)2 * 16 * STRIDE * sizeof(float)) return;

    const float* x   = (const float*)d_in[0];
    const float* w0  = (const float*)d_in[1];
    const float* b0  = (const float*)d_in[2];
    const float* wm  = (const float*)d_in[3];
    const float* bm  = (const float*)d_in[4];
    const float* w18 = (const float*)d_in[5];
    const float* b18 = (const float*)d_in[6];
    const float* w19 = (const float*)d_in[7];
    const float* b19 = (const float*)d_in[8];
    const float* a1  = (const float*)d_in[9];
    const float* a2  = (const float*)d_in[10];
    const float* Wfc = (const float*)d_in[11];
    const float* bfc = (const float*)d_in[12];

    float* b1 = (float*)d_ws;
    float* b2 = b1 + (size_t)16*STRIDE;

    // ---- layer 0: conv(99, pad 98) -> fold(x2 dup) -> kmax 262144 -> PReLU(a1) ----
    conv0_k<<<dim3((262242 + 255)/256, 8), 256, 0, stream>>>(x, b1, w0, b0);
    sort_cols<<<16, SBT, 0, stream>>>((u32*)b1, (u32*)b2, b1, a1, 262242, 262144, 2, ACT_PRELU);
    float* I = b1;
    int Hin = 262144;

    // ---- layers 1..17: conv(9, pad 8) -> kmax -> PReLU(a2)/ReLU ----
    static const int ks[17] = {249036,235929,222822,209715,196608,183500,170393,157286,
                               144179,131072,117964,104857,91750,78643,65536,52428,39321};
    for (int i = 0; i < 17; i++){
        float* O = (I == b1) ? b2 : b1;
        int Hout = Hin + 8;
        conv_t<2,2><<<dim3((Hout + 255)/256, 8), 256, 0, stream>>>(
            I, O, wm + (size_t)i*36, bm + (size_t)i*2, Hin, Hout, 9, 8, 8, 8, 0, 1.f);
        sort_cols<<<16, SBT, 0, stream>>>((u32*)O, (u32*)I, O, a2, Hout, ks[i], 1,
                                          (i == 0) ? ACT_PRELU : ACT_RELU);
        I = O; Hin = ks[i];
    }

    // ---- layer 18: conv(9) -> fold(widths 8->4, x2 dup) -> kmax 26214 -> ELU ----
    {
        float* O = (I == b1) ? b2 : b1;
        int Hout = Hin + 8;   // 39329
        conv_t<2,2><<<dim3((Hout + 255)/256, 4), 256, 0, stream>>>(
            I, O, w18, b18, Hin, Hout, 9, 8, 8, 4, 1, 2.f);
        sort_cols<<<8, SBT, 0, stream>>>((u32*)O, (u32*)I, O, a2, Hout, 26214, 2, ACT_ELU);
        I = O; Hin = 26214;
    }

    // ---- layer 19: conv(358, pad 357, 2->5ch) -> fold(widths 4->2, x5 dup) -> kmax 800 -> ELU ----
    {
        float* O = (I == b1) ? b2 : b1;
        int Hout = Hin + 714 - 358 + 1;   // 26571
        conv_t<2,5><<<dim3((Hout + 255)/256, 2), 256, 0, stream>>>(
            I, O, w19, b19, Hin, Hout, 358, 357, 4, 2, 1, 2.f);
        sort_cols<<<10, SBT, 0, stream>>>((u32*)O, (u32*)I, O, a2, Hout, 800, 5, ACT_ELU);
        I = O;
    }

    // ---- FC + log_softmax ----
    fc_lsm<<<1, 1024, 0, stream>>>(I, Wfc, bfc, (float*)d_out);
}

// Round 3
// 2220.281 us; speedup vs baseline: 12.8777x; 12.8777x over previous
//
#include <hip/hip_runtime.h>
#include <hip/hip_bf16.h>
#include <math.h>

typedef unsigned int u32;
typedef unsigned long long u64;

#define STRIDE 262656          // per-column stride in floats (>= max column length 262242)
#define NBINS  262144          // 18-bit key space
#define KSHIFT 14
#define KROUND 0x2000u
#define ACT_PRELU 0
#define ACT_RELU  1
#define ACT_ELU   2

// float -> key such that ascending key order == descending float order
__device__ __forceinline__ u32 f2k(float f){
    u32 u = __float_as_uint(f);
    return (u & 0x80000000u) ? u : (u ^ 0x7FFFFFFFu);
}
__device__ __forceinline__ float k2f(u32 k){
    u32 u = (k & 0x80000000u) ? k : (k ^ 0x7FFFFFFFu);
    return __uint_as_float(u);
}

// ---------------- layer-0 conv: x[262144][16] -> fold widths -> conv K=99 pad=98 ----------------
__global__ __launch_bounds__(256) void conv0_k(const float* __restrict__ x, float* __restrict__ Out,
                                               const float* __restrict__ w0, const float* __restrict__ b0)
{
    __shared__ float s0[354];
    __shared__ float sw[198];
    const int wp = blockIdx.y;
    const int h0 = blockIdx.x * 256;
    const int tid = threadIdx.x;
    for (int t = tid; t < 354; t += 256){
        int h = h0 - 98 + t;
        float v = 0.f;
        if (h >= 0 && h < 262144) v = x[(size_t)h*16 + 2*wp] + x[(size_t)h*16 + 2*wp + 1];
        s0[t] = v;
    }
    if (tid < 198) sw[tid] = w0[tid];
    __syncthreads();
    int hp = h0 + tid;
    if (hp < 262242){
        float a0 = 2.f*b0[0], a1v = 2.f*b0[1];   // fold doubles bias
        for (int j = 0; j < 99; j++){
            float xv = s0[tid + j];
            a0  += sw[j]      * xv;
            a1v += sw[99 + j] * xv;
        }
        Out[(size_t)(0*8 + wp)*STRIDE + hp] = a0;
        Out[(size_t)(1*8 + wp)*STRIDE + hp] = a1v;
    }
}

// ---------------- generic conv along H, column-major buffers ----------------
template<int INC, int OUTC>
__global__ __launch_bounds__(256) void conv_t(
    const float* __restrict__ In, float* __restrict__ Out,
    const float* __restrict__ Wt, const float* __restrict__ Bs,
    int Hin, int Hout, int K, int pad, int Wi, int Wo, int foldIn, float bscale)
{
    __shared__ float sIn[INC][613];
    __shared__ float sW[OUTC*INC*358];
    const int wp = blockIdx.y;
    const int h0 = blockIdx.x * 256;
    const int tid = threadIdx.x;
    const int tl = 256 + K - 1;
    for (int t = tid; t < INC*tl; t += 256){
        int c = t / tl, r = t - c*tl;
        int h = h0 - pad + r;
        float v = 0.f;
        if (h >= 0 && h < Hin){
            if (foldIn) v = In[(size_t)(c*Wi + 2*wp)*STRIDE + h] + In[(size_t)(c*Wi + 2*wp + 1)*STRIDE + h];
            else        v = In[(size_t)(c*Wi + wp)*STRIDE + h];
        }
        sIn[c][r] = v;
    }
    for (int t = tid; t < OUTC*INC*K; t += 256) sW[t] = Wt[t];
    __syncthreads();
    int hp = h0 + tid;
    if (hp < Hout){
        float acc[OUTC];
        #pragma unroll
        for (int o = 0; o < OUTC; o++) acc[o] = bscale * Bs[o];
        for (int c = 0; c < INC; c++){
            for (int j = 0; j < K; j++){
                float xv = sIn[c][tid + j];
                #pragma unroll
                for (int o = 0; o < OUTC; o++) acc[o] += sW[(o*INC + c)*K + j] * xv;
            }
        }
        #pragma unroll
        for (int o = 0; o < OUTC; o++) Out[(size_t)(o*Wo + wp)*STRIDE + hp] = acc[o];
    }
}

// ---------------- histogram-based counting "sort" ----------------

// zero NBINS bins per column (H laid out as col*STRIDE u32s)
__global__ __launch_bounds__(256) void hzero(u32* __restrict__ H)
{
    u32* Hc = H + (size_t)blockIdx.y * STRIDE;
    uint4 z = make_uint4(0,0,0,0);
    int stride = gridDim.x * 256;
    for (int i = blockIdx.x*256 + threadIdx.x; i < NBINS/4; i += stride)
        ((uint4*)Hc)[i] = z;
}

// per-column 18-bit-key histogram with wave run-length dedup
__global__ __launch_bounds__(256) void hist_k(const float* __restrict__ In, u32* __restrict__ H, int N)
{
    const int col = blockIdx.y;
    const float* src = In + (size_t)col*STRIDE;
    u32* Hc = H + (size_t)col*STRIDE;
    const int lane = threadIdx.x & 63;
    const int stride = gridDim.x * 256;
    const int iters = (N + stride - 1) / stride;
    int i = blockIdx.x*256 + threadIdx.x;
    for (int it = 0; it < iters; it++, i += stride){
        bool val = (i < N);
        u32 k18 = 0xFFFFFFFFu;
        if (val){
            u32 k32 = f2k(src[i]);
            u64 kr = ((u64)k32 + KROUND) >> KSHIFT;
            k18 = (u32)(kr > (u64)(NBINS-1) ? (u64)(NBINS-1) : kr);
        }
        u32 prev = __shfl_up(k18, 1);
        bool diff = (lane == 0) || (prev != k18);
        u64 m = __ballot(diff || !val);
        if (val && diff){
            u64 above = m & ~((2ull << lane) - 1ull);   // break points strictly above my lane
            int nxt = above ? (__ffsll((unsigned long long)above) - 1) : 64;
            atomicAdd(&Hc[k18], (u32)(nxt - lane));
        }
    }
}

// scan stage 1: per 1024-bin block inclusive scan; block totals to aux (= col base + NBINS)
__global__ __launch_bounds__(256) void hscan1(u32* __restrict__ H)
{
    u32* P = H + (size_t)blockIdx.y * STRIDE;
    u32* aux = P + NBINS;
    const int b = blockIdx.x, tid = threadIdx.x;
    const int base = b*1024 + tid*4;
    uint4 v = *(uint4*)(P + base);
    u32 s0 = v.x, s1 = s0 + v.y, s2 = s1 + v.z, s3 = s2 + v.w;
    __shared__ u32 sc[256];
    sc[tid] = s3;
    __syncthreads();
    for (int ofs = 1; ofs < 256; ofs <<= 1){
        u32 t = (tid >= ofs) ? sc[tid - ofs] : 0u;
        __syncthreads();
        sc[tid] += t;
        __syncthreads();
    }
    u32 excl = sc[tid] - s3;
    uint4 o = make_uint4(excl + s0, excl + s1, excl + s2, excl + s3);
    *(uint4*)(P + base) = o;
    if (tid == 255) aux[b] = sc[255];
}

// scan stage 2: add exclusive prefix of block totals (computed by in-block reduction)
__global__ __launch_bounds__(256) void hscan2(u32* __restrict__ H)
{
    u32* P = H + (size_t)blockIdx.y * STRIDE;
    u32* aux = P + NBINS;
    const int b = blockIdx.x, tid = threadIdx.x;
    __shared__ u32 sc[256];
    sc[tid] = (tid < b) ? aux[tid] : 0u;
    __syncthreads();
    for (int s = 128; s > 0; s >>= 1){
        if (tid < s) sc[tid] += sc[tid + s];
        __syncthreads();
    }
    u32 off = sc[0];
    if (b == 0 || off == 0) return;
    const int base = b*1024 + tid*4;
    uint4 v = *(uint4*)(P + base);
    v.x += off; v.y += off; v.z += off; v.w += off;
    *(uint4*)(P + base) = v;
}

// reconstruct sorted / truncated / activated / dup'd output from inclusive prefix P
__global__ __launch_bounds__(256) void reconstruct(
    const u32* __restrict__ H, float* __restrict__ dst,
    const float* __restrict__ alphaPtr, int kOut, int dup, int act)
{
    const int col = blockIdx.y;
    const u32* P = H + (size_t)col*STRIDE;
    float* d = dst + (size_t)col*STRIDE;
    const int nr = kOut / dup;
    const float alpha = alphaPtr[0];
    const int stride = gridDim.x * 256;
    for (int r = blockIdx.x*256 + threadIdx.x; r < nr; r += stride){
        // smallest b with P[b] > r
        int lo = 0, hi = NBINS - 1;
        while (lo < hi){
            int mid = (lo + hi) >> 1;
            if (P[mid] > (u32)r) hi = mid; else lo = mid + 1;
        }
        float v = k2f(((u32)lo) << KSHIFT);   // bin center in key space
        if (act == ACT_PRELU)      v = (v >= 0.f) ? v : alpha * v;
        else if (act == ACT_RELU)  v = (v > 0.f) ? v : 0.f;
        else                       v = (v > 0.f) ? v : expm1f(v);
        int bse = r * dup;
        for (int dd = 0; dd < dup; dd++) d[bse + dd] = v;
    }
}

// ---------------- FC (5x1600 @ 1600x200) + log_softmax over 1000 ----------------
__global__ __launch_bounds__(1024) void fc_lsm(const float* __restrict__ A, const float* __restrict__ Wfc,
                                               const float* __restrict__ bfc, float* __restrict__ out)
{
    const int tid = threadIdx.x;
    __shared__ float red[1024];
    float logit = -INFINITY;
    if (tid < 1000){
        int o = tid / 200, j = tid - o*200;
        float acc = bfc[j];
        const float* wrow = Wfc + (size_t)j*1600;
        for (int q = 0; q < 1600; q++){
            int p = q >> 1, wq = q & 1;
            acc += wrow[q] * A[(size_t)(o*2 + wq)*STRIDE + p];
        }
        logit = acc;
    }
    red[tid] = logit;
    __syncthreads();
    for (int s = 512; s > 0; s >>= 1){
        if (tid < s) red[tid] = fmaxf(red[tid], red[tid + s]);
        __syncthreads();
    }
    float m = red[0];
    __syncthreads();
    red[tid] = (tid < 1000) ? expf(logit - m) : 0.f;
    __syncthreads();
    for (int s = 512; s > 0; s >>= 1){
        if (tid < s) red[tid] += red[tid + s];
        __syncthreads();
    }
    float lse = logf(red[0]);
    if (tid < 1000) out[tid] = logit - m - lse;
}

// helper: run hist-sort pipeline. O = conv output (cols columns, N rows);
// Hb = dead buffer used for bins; result written into O[0..kOut) per column.
static void hist_sort(float* O, float* Hb, const float* alphaPtr,
                      int N, int kOut, int dup, int act, int cols, hipStream_t stream)
{
    u32* H = (u32*)Hb;
    hzero  <<<dim3(64, cols), 256, 0, stream>>>(H);
    hist_k <<<dim3(128, cols), 256, 0, stream>>>(O, H, N);
    hscan1 <<<dim3(256, cols), 256, 0, stream>>>(H);
    hscan2 <<<dim3(256, cols), 256, 0, stream>>>(H);
    reconstruct<<<dim3(64, cols), 256, 0, stream>>>(H, O, alphaPtr, kOut, dup, act);
}

extern "C" void kernel_launch(void* const* d_in, const int* in_sizes, int n_in,
                              void* d_out, int out_size, void* d_ws, size_t ws_size,
                              hipStream_t stream)
{
    (void)in_sizes; (void)n_in; (void)out_size;
    if (ws_size < (size_t)2 * 16 * STRIDE * sizeof(float)) return;

    const float* x   = (const float*)d_in[0];
    const float* w0  = (const float*)d_in[1];
    const float* b0  = (const float*)d_in[2];
    const float* wm  = (const float*)d_in[3];
    const float* bm  = (const float*)d_in[4];
    const float* w18 = (const float*)d_in[5];
    const float* b18 = (const float*)d_in[6];
    const float* w19 = (const float*)d_in[7];
    const float* b19 = (const float*)d_in[8];
    const float* a1  = (const float*)d_in[9];
    const float* a2  = (const float*)d_in[10];
    const float* Wfc = (const float*)d_in[11];
    const float* bfc = (const float*)d_in[12];

    float* b1 = (float*)d_ws;
    float* b2 = b1 + (size_t)16*STRIDE;

    // ---- layer 0: conv(99, pad 98) -> fold(x2 dup) -> kmax 262144 -> PReLU(a1) ----
    conv0_k<<<dim3((262242 + 255)/256, 8), 256, 0, stream>>>(x, b1, w0, b0);
    hist_sort(b1, b2, a1, 262242, 262144, 2, ACT_PRELU, 16, stream);
    float* I = b1;
    int Hin = 262144;

    // ---- layers 1..17: conv(9, pad 8) -> kmax -> PReLU(a2)/ReLU ----
    static const int ks[17] = {249036,235929,222822,209715,196608,183500,170393,157286,
                               144179,131072,117964,104857,91750,78643,65536,52428,39321};
    for (int i = 0; i < 17; i++){
        float* O = (I == b1) ? b2 : b1;
        int Hout = Hin + 8;
        conv_t<2,2><<<dim3((Hout + 255)/256, 8), 256, 0, stream>>>(
            I, O, wm + (size_t)i*36, bm + (size_t)i*2, Hin, Hout, 9, 8, 8, 8, 0, 1.f);
        hist_sort(O, I, a2, Hout, ks[i], 1, (i == 0) ? ACT_PRELU : ACT_RELU, 16, stream);
        I = O; Hin = ks[i];
    }

    // ---- layer 18: conv(9) -> fold(widths 8->4, x2 dup) -> kmax 26214 -> ELU ----
    {
        float* O = (I == b1) ? b2 : b1;
        int Hout = Hin + 8;   // 39329
        conv_t<2,2><<<dim3((Hout + 255)/256, 4), 256, 0, stream>>>(
            I, O, w18, b18, Hin, Hout, 9, 8, 8, 4, 1, 2.f);
        hist_sort(O, I, a2, Hout, 26214, 2, ACT_ELU, 8, stream);
        I = O; Hin = 26214;
    }

    // ---- layer 19: conv(358, pad 357, 2->5ch) -> fold(widths 4->2, x5 dup) -> kmax 800 -> ELU ----
    {
        float* O = (I == b1) ? b2 : b1;
        int Hout = Hin + 714 - 358 + 1;   // 26571
        conv_t<2,5><<<dim3((Hout + 255)/256, 2), 256, 0, stream>>>(
            I, O, w19, b19, Hin, Hout, 358, 357, 4, 2, 1, 2.f);
        hist_sort(O, I, a2, Hout, 800, 5, ACT_ELU, 10, stream);
        I = O;
    }

    // ---- FC + log_softmax ----
    fc_lsm<<<1, 1024, 0, stream>>>(I, Wfc, bfc, (float*)d_out);
}

// Round 4
// 1800.139 us; speedup vs baseline: 15.8833x; 1.2334x over previous
//
#include <hip/hip_runtime.h>
#include <hip/hip_bf16.h>
#include <math.h>

typedef unsigned int u32;
typedef unsigned long long u64;

#define STRIDE 262656          // per-column stride in floats (>= max column length 262242)
#define KSHIFT 14
#define KROUND 0x2000u
#define BAND   12288           // 24 exponents x 512 mantissa steps per sign
#define NB     24576           // total bins per column (2 bands)
#define PA18   0xE200u         // (f2k(65535.97) >> 14): positive band base
#define NA18   0x2EE00u        // (f2k(-2^-8)   >> 14): negative band base
#define NCOLS  16
#define ZW4    (NB*NCOLS/4)    // uint4 words to zero a bin buffer
#define ACT_PRELU 0
#define ACT_RELU  1
#define ACT_ELU   2

__device__ __forceinline__ float k2f(u32 k){
    u32 u = (k & 0x80000000u) ? k : (k ^ 0x7FFFFFFFu);
    return __uint_as_float(u);
}

// monotone 18-bit quantization: bin 0 = largest float, NB-1 = most negative
__device__ __forceinline__ int bin_of(float v){
    float av = fabsf(v);
    av = fminf(fmaxf(av, 0.00390625f), 65535.96875f);
    u32 u = __float_as_uint(av);
    if (v < 0.f){
        u32 k = 0x80000000u | u;
        int b = (int)(((k + KROUND) >> KSHIFT) - NA18);
        b = b < 0 ? 0 : (b > BAND-1 ? BAND-1 : b);
        return BAND + b;
    } else {
        u32 k = u ^ 0x7FFFFFFFu;
        int b = (int)(((k + KROUND) >> KSHIFT) - PA18);
        b = b < 0 ? 0 : (b > BAND-1 ? BAND-1 : b);
        return b;
    }
}
__device__ __forceinline__ float bin_val(int bin){
    u32 k18 = (bin < BAND) ? ((u32)bin + PA18) : ((u32)(bin - BAND) + NA18);
    return k2f(k18 << KSHIFT);
}

// wave run-length-dedup'd histogram add (input near-sorted -> long runs)
__device__ __forceinline__ void hist_add(u32* __restrict__ Hc, int bin, bool valid, int lane){
    u32 bn = valid ? (u32)bin : 0xFFFFFFFFu;
    u32 prev = __shfl_up(bn, 1);
    bool diff = (lane == 0) || (prev != bn);
    u64 m = __ballot(diff || !valid);
    if (valid && diff){
        u64 above = m & ~((2ull << lane) - 1ull);
        int nxt = above ? (__ffsll((unsigned long long)above) - 1) : 64;
        atomicAdd(&Hc[bin], (u32)(nxt - lane));
    }
}

// ---------------- layer-0 fused conv+hist: x[262144][16] -> fold -> conv K=99 pad=98 -> bins ----
__global__ __launch_bounds__(256) void conv0_hist(const float* __restrict__ x, u32* __restrict__ H,
                                                  const float* __restrict__ w0, const float* __restrict__ b0)
{
    __shared__ float s0[354];
    __shared__ float sw[198];
    const int wp = blockIdx.y;
    const int h0 = blockIdx.x * 256;
    const int tid = threadIdx.x;
    const int lane = tid & 63;
    for (int t = tid; t < 354; t += 256){
        int h = h0 - 98 + t;
        float v = 0.f;
        if (h >= 0 && h < 262144) v = x[(size_t)h*16 + 2*wp] + x[(size_t)h*16 + 2*wp + 1];
        s0[t] = v;
    }
    if (tid < 198) sw[tid] = w0[tid];
    __syncthreads();
    int hp = h0 + tid;
    bool valid = (hp < 262242);
    float a0 = 2.f*b0[0], a1v = 2.f*b0[1];   // fold doubles bias
    for (int j = 0; j < 99; j++){
        float xv = s0[tid + j];
        a0  += sw[j]      * xv;
        a1v += sw[99 + j] * xv;
    }
    hist_add(H + (size_t)(0*8 + wp)*NB, bin_of(a0),  valid, lane);
    hist_add(H + (size_t)(1*8 + wp)*NB, bin_of(a1v), valid, lane);
}

// ---------------- generic fused conv+hist along H ----------------
// In col layout: (c*Wi + w)*STRIDE + h.  Hist col: (o*Wo + wp)*NB.
template<int INC, int OUTC>
__global__ __launch_bounds__(256) void conv_hist_t(
    const float* __restrict__ In, u32* __restrict__ H,
    const float* __restrict__ Wt, const float* __restrict__ Bs,
    int Hin, int Hout, int K, int pad, int Wi, int Wo, int foldIn, float bscale)
{
    __shared__ float sIn[INC][613];
    __shared__ float sW[OUTC*INC*358];
    const int wp = blockIdx.y;
    const int h0 = blockIdx.x * 256;
    const int tid = threadIdx.x;
    const int lane = tid & 63;
    const int tl = 256 + K - 1;
    for (int t = tid; t < INC*tl; t += 256){
        int c = t / tl, r = t - c*tl;
        int h = h0 - pad + r;
        float v = 0.f;
        if (h >= 0 && h < Hin){
            if (foldIn) v = In[(size_t)(c*Wi + 2*wp)*STRIDE + h] + In[(size_t)(c*Wi + 2*wp + 1)*STRIDE + h];
            else        v = In[(size_t)(c*Wi + wp)*STRIDE + h];
        }
        sIn[c][r] = v;
    }
    for (int t = tid; t < OUTC*INC*K; t += 256) sW[t] = Wt[t];
    __syncthreads();
    int hp = h0 + tid;
    bool valid = (hp < Hout);
    float acc[OUTC];
    #pragma unroll
    for (int o = 0; o < OUTC; o++) acc[o] = bscale * Bs[o];
    for (int c = 0; c < INC; c++){
        for (int j = 0; j < K; j++){
            float xv = sIn[c][tid + j];
            #pragma unroll
            for (int o = 0; o < OUTC; o++) acc[o] += sW[(o*INC + c)*K + j] * xv;
        }
    }
    #pragma unroll
    for (int o = 0; o < OUTC; o++)
        hist_add(H + (size_t)(o*Wo + wp)*NB, bin_of(acc[o]), valid, lane);
}

// ---------------- single-kernel inclusive scan of NB bins per column ----------------
__global__ __launch_bounds__(1024) void hscan(u32* __restrict__ H)
{
    u32* P = H + (size_t)blockIdx.x * NB;
    const int tid = threadIdx.x;
    const int base = tid * 24;
    u32 v[24];
    u32 s = 0;
    #pragma unroll
    for (int i = 0; i < 24; i++){ v[i] = P[base + i]; s += v[i]; v[i] = s; }
    __shared__ u32 sc[1024];
    sc[tid] = s;
    __syncthreads();
    for (int ofs = 1; ofs < 1024; ofs <<= 1){
        u32 t = (tid >= ofs) ? sc[tid - ofs] : 0u;
        __syncthreads();
        sc[tid] += t;
        __syncthreads();
    }
    u32 excl = sc[tid] - s;
    #pragma unroll
    for (int i = 0; i < 24; i++) P[base + i] = v[i] + excl;
}

// ---------------- reconstruct sorted/truncated/activated/dup'd output; zero next bins ----------------
__global__ __launch_bounds__(256) void reconstruct(
    const u32* __restrict__ H, float* __restrict__ dst,
    const float* __restrict__ alphaPtr, int kOut, int dup, int act,
    uint4* __restrict__ zb)
{
    const int col = blockIdx.y;
    const u32* P = H + (size_t)col*NB;
    float* d = dst + (size_t)col*STRIDE;
    const int nr = kOut / dup;
    const float alpha = alphaPtr[0];
    const int stride = gridDim.x * 256;
    for (int r = blockIdx.x*256 + threadIdx.x; r < nr; r += stride){
        int lo = 0, hi = NB - 1;
        while (lo < hi){
            int mid = (lo + hi) >> 1;
            if (P[mid] > (u32)r) hi = mid; else lo = mid + 1;
        }
        float v = bin_val(lo);
        if (act == ACT_PRELU)      v = (v >= 0.f) ? v : alpha * v;
        else if (act == ACT_RELU)  v = (v > 0.f) ? v : 0.f;
        else                       v = (v > 0.f) ? v : expm1f(v);
        int bse = r * dup;
        for (int dd = 0; dd < dup; dd++) d[bse + dd] = v;
    }
    // fused zeroing of the other bin buffer for the next layer
    const uint4 z = make_uint4(0,0,0,0);
    int lin = (blockIdx.y * gridDim.x + blockIdx.x) * 256 + threadIdx.x;
    int tot = gridDim.x * gridDim.y * 256;
    for (int i = lin; i < ZW4; i += tot) zb[i] = z;
}

__global__ __launch_bounds__(256) void hzero(uint4* __restrict__ zb)
{
    const uint4 z = make_uint4(0,0,0,0);
    int lin = blockIdx.x * 256 + threadIdx.x;
    int tot = gridDim.x * 256;
    for (int i = lin; i < ZW4; i += tot) zb[i] = z;
}

// ---------------- FC: 1000 logits, one block each ----------------
__global__ __launch_bounds__(256) void fc_dot(const float* __restrict__ A, const float* __restrict__ Wfc,
                                              const float* __restrict__ bfc, float* __restrict__ logits)
{
    const int t = blockIdx.x;            // 0..999
    const int o = t / 200, j = t - o*200;
    const float* wrow = Wfc + (size_t)j*1600;
    float acc = 0.f;
    for (int q = threadIdx.x; q < 1600; q += 256){
        int p = q >> 1, wq = q & 1;
        acc += wrow[q] * A[(size_t)(o*2 + wq)*STRIDE + p];
    }
    __shared__ float red[256];
    red[threadIdx.x] = acc;
    __syncthreads();
    for (int s = 128; s > 0; s >>= 1){
        if (threadIdx.x < s) red[threadIdx.x] += red[threadIdx.x + s];
        __syncthreads();
    }
    if (threadIdx.x == 0) logits[t] = red[0] + bfc[j];
}

__global__ __launch_bounds__(1024) void lsm(const float* __restrict__ logits, float* __restrict__ out)
{
    const int tid = threadIdx.x;
    __shared__ float red[1024];
    float lg = (tid < 1000) ? logits[tid] : -INFINITY;
    red[tid] = lg;
    __syncthreads();
    for (int s = 512; s > 0; s >>= 1){
        if (tid < s) red[tid] = fmaxf(red[tid], red[tid + s]);
        __syncthreads();
    }
    float m = red[0];
    __syncthreads();
    red[tid] = (tid < 1000) ? expf(lg - m) : 0.f;
    __syncthreads();
    for (int s = 512; s > 0; s >>= 1){
        if (tid < s) red[tid] += red[tid + s];
        __syncthreads();
    }
    float lse = logf(red[0]);
    if (tid < 1000) out[tid] = lg - m - lse;
}

extern "C" void kernel_launch(void* const* d_in, const int* in_sizes, int n_in,
                              void* d_out, int out_size, void* d_ws, size_t ws_size,
                              hipStream_t stream)
{
    (void)in_sizes; (void)n_in; (void)out_size;
    const size_t need = (size_t)16*STRIDE*4 + (size_t)2*NB*NCOLS*4 + 4096;
    if (ws_size < need) return;

    const float* x   = (const float*)d_in[0];
    const float* w0  = (const float*)d_in[1];
    const float* b0  = (const float*)d_in[2];
    const float* wm  = (const float*)d_in[3];
    const float* bm  = (const float*)d_in[4];
    const float* w18 = (const float*)d_in[5];
    const float* b18 = (const float*)d_in[6];
    const float* w19 = (const float*)d_in[7];
    const float* b19 = (const float*)d_in[8];
    const float* a1  = (const float*)d_in[9];
    const float* a2  = (const float*)d_in[10];
    const float* Wfc = (const float*)d_in[11];
    const float* bfc = (const float*)d_in[12];

    float* b1   = (float*)d_ws;
    u32*  bin0  = (u32*)(b1 + (size_t)16*STRIDE);
    u32*  bin1  = bin0 + (size_t)NB*NCOLS;
    float* logits = (float*)(bin1 + (size_t)NB*NCOLS);

    u32* cur = bin0;
    u32* nxt = bin1;

    hzero<<<384, 256, 0, stream>>>((uint4*)cur);

    // ---- layer 0: conv(99, pad 98) -> fold(x2 dup) -> kmax 262144 -> PReLU(a1) ----
    conv0_hist<<<dim3((262242 + 255)/256, 8), 256, 0, stream>>>(x, cur, w0, b0);
    hscan<<<16, 1024, 0, stream>>>(cur);
    reconstruct<<<dim3(128, 16), 256, 0, stream>>>(cur, b1, a1, 262144, 2, ACT_PRELU, (uint4*)nxt);
    { u32* t = cur; cur = nxt; nxt = t; }
    int Hin = 262144;

    // ---- layers 1..17: conv(9, pad 8) -> kmax -> PReLU(a2)/ReLU ----
    static const int ks[17] = {249036,235929,222822,209715,196608,183500,170393,157286,
                               144179,131072,117964,104857,91750,78643,65536,52428,39321};
    for (int i = 0; i < 17; i++){
        int Hout = Hin + 8;
        conv_hist_t<2,2><<<dim3((Hout + 255)/256, 8), 256, 0, stream>>>(
            b1, cur, wm + (size_t)i*36, bm + (size_t)i*2, Hin, Hout, 9, 8, 8, 8, 0, 1.f);
        hscan<<<16, 1024, 0, stream>>>(cur);
        reconstruct<<<dim3(128, 16), 256, 0, stream>>>(cur, b1, a2, ks[i], 1,
                                                       (i == 0) ? ACT_PRELU : ACT_RELU, (uint4*)nxt);
        { u32* t = cur; cur = nxt; nxt = t; }
        Hin = ks[i];
    }

    // ---- layer 18: conv(9) -> fold(widths 8->4, x2 dup) -> kmax 26214 -> ELU ----
    {
        int Hout = Hin + 8;   // 39329
        conv_hist_t<2,2><<<dim3((Hout + 255)/256, 4), 256, 0, stream>>>(
            b1, cur, w18, b18, Hin, Hout, 9, 8, 8, 4, 1, 2.f);
        hscan<<<8, 1024, 0, stream>>>(cur);
        reconstruct<<<dim3(128, 8), 256, 0, stream>>>(cur, b1, a2, 26214, 2, ACT_ELU, (uint4*)nxt);
        { u32* t = cur; cur = nxt; nxt = t; }
        Hin = 26214;
    }

    // ---- layer 19: conv(358, pad 357, 2->5ch) -> fold(widths 4->2, x5 dup) -> kmax 800 -> ELU ----
    {
        int Hout = Hin + 714 - 358 + 1;   // 26571
        conv_hist_t<2,5><<<dim3((Hout + 255)/256, 2), 256, 0, stream>>>(
            b1, cur, w19, b19, Hin, Hout, 358, 357, 4, 2, 1, 2.f);
        hscan<<<10, 1024, 0, stream>>>(cur);
        reconstruct<<<dim3(16, 10), 256, 0, stream>>>(cur, b1, a2, 800, 5, ACT_ELU, (uint4*)nxt);
    }

    // ---- FC + log_softmax ----
    fc_dot<<<1000, 256, 0, stream>>>(b1, Wfc, bfc, logits);
    lsm<<<1, 1024, 0, stream>>>(logits, (float*)d_out);
}